// Round 1
// baseline (561.975 us; speedup 1.0000x reference)
//
#include <hip/hip_runtime.h>
#include <math.h>

#define NUM_K   1024
#define CDIM    64
#define HW      1024          // 32*32
#define NROWS   65536         // 64*1024
#define NBLK    1024          // epilogue blocks (64 rows each) — keeps partials structure
#define EPAD    200           // padded split-row stride in bf16 elems (400 B, 16B-granular)
#define EPS_THR 1.0e-4f       // candidate threshold on g~ = nk - 2*dot~

using bf16x8 = __attribute__((ext_vector_type(8))) short;
using f32x4  = __attribute__((ext_vector_type(4))) float;
using gcptr  = const __attribute__((address_space(1))) void*;
using lptr   = __attribute__((address_space(3))) void*;

// numpy pairwise_sum order for n=64 contiguous fp32 (8 stride-8 chains),
// squares rounded separately (no FMA). Bit-matches np.sum(x*x, axis=1).
__device__ __forceinline__ float np_sumsq64(const float* a) {
#pragma clang fp contract(off)
  float r0 = a[0]*a[0], r1 = a[1]*a[1], r2 = a[2]*a[2], r3 = a[3]*a[3];
  float r4 = a[4]*a[4], r5 = a[5]*a[5], r6 = a[6]*a[6], r7 = a[7]*a[7];
#pragma unroll
  for (int i = 8; i < 64; i += 8) {
    r0 += a[i+0]*a[i+0]; r1 += a[i+1]*a[i+1];
    r2 += a[i+2]*a[i+2]; r3 += a[i+3]*a[i+3];
    r4 += a[i+4]*a[i+4]; r5 += a[i+5]*a[i+5];
    r6 += a[i+6]*a[i+6]; r7 += a[i+7]*a[i+7];
  }
  return ((r0+r1)+(r2+r3))+((r4+r5)+(r6+r7));
}

// Pass 0: exact norms + split codebook e' = [e_hi | e_hi | e_lo] (bf16 trunc split),
// padded to EPAD, written row-contiguous so chunk staging is a linear copy.
__global__ void vq_prep(const float* __restrict__ emb, float* __restrict__ norms,
                        unsigned short* __restrict__ esp)
{
  const int k = blockIdx.x * blockDim.x + threadIdx.x;
  if (k >= NUM_K) return;
  norms[k] = np_sumsq64(emb + k * CDIM);
  unsigned short* row = esp + (size_t)k * EPAD;
  for (int c = 0; c < CDIM; ++c) {
    const float v = emb[k * CDIM + c];
    const unsigned int vb = __float_as_uint(v);
    const unsigned short h = (unsigned short)(vb >> 16);           // bf16 trunc
    const float res = v - __uint_as_float((unsigned int)h << 16);
    const unsigned short l = (unsigned short)(__float_as_uint(res) >> 16);
    row[c] = h; row[64 + c] = h; row[128 + c] = l;
  }
  for (int i = 192; i < EPAD; ++i) row[i] = 0;
}

// Pass 1: split-bf16 MFMA distance filter.
// Virtual GEMM: dot~ = [x_hi|x_lo|x_hi](64 rows x 192) . [e_hi|e_hi|e_lo]^T (1024 x 192).
// Per row track two smallest g~ = nk - 2*dot~ and argmin; flag rows with gap <= EPS.
// Note: A and B fragments are packed with the SAME slot->c mapping, so the result is
// invariant to the HW's internal K-slot permutation. C layout: col=lane&15,
// row=(lane>>4)*4+reg [HW-verified].
__global__ __launch_bounds__(256, 2)
void vq_dist(const float* __restrict__ xin, const float* __restrict__ norms,
             const unsigned short* __restrict__ esp, float* __restrict__ out_idx)
{
  __shared__ __align__(16) unsigned short A_s[64 * EPAD];    // 25600 B
  __shared__ __align__(16) unsigned short B_s[128 * EPAD];   // 51200 B
  __shared__ float red_m1[4][64];
  __shared__ float red_m2[4][64];
  __shared__ int   red_k1[4][64];

  const int t    = threadIdx.x;
  const int lane = t & 63;
  const int w    = t >> 6;        // wave id = 32-col slice of each 128-col chunk
  const int l15  = lane & 15;
  const int g4   = lane >> 4;

  const int n0  = blockIdx.x * 64;
  const int b   = n0 >> 10;
  const int hw0 = n0 & (HW - 1);

  // ---- stage A: load x (coalesced across rows), trunc-split, pack [hi|lo|hi] ----
  {
    const int r = t & 63, q = t >> 6;             // row, 16-channel quarter
    const float* xb = xin + (size_t)b * (CDIM * HW) + hw0 + r;
    unsigned short* arow = A_s + r * EPAD;
#pragma unroll
    for (int u = 0; u < 8; ++u) {
      const int c0 = q * 16 + 2 * u;
      const float v0 = xb[(size_t)c0 * HW];
      const float v1 = xb[(size_t)(c0 + 1) * HW];
      const unsigned int h0 = __float_as_uint(v0) >> 16;
      const unsigned int h1 = __float_as_uint(v1) >> 16;
      const float r0 = v0 - __uint_as_float(h0 << 16);
      const float r1 = v1 - __uint_as_float(h1 << 16);
      const unsigned int lo0 = __float_as_uint(r0) >> 16;
      const unsigned int lo1 = __float_as_uint(r1) >> 16;
      const unsigned int hh = h0 | (h1 << 16);
      const unsigned int ll = lo0 | (lo1 << 16);
      *(unsigned int*)(arow + c0)        = hh;   // slots [0,64):   x_hi
      *(unsigned int*)(arow + 64 + c0)   = ll;   // slots [64,128): x_lo
      *(unsigned int*)(arow + 128 + c0)  = hh;   // slots [128,192):x_hi
    }
  }

  // ---- async chunk staging: 128 codes * 400 B = 51200 B linear copy ----
  auto stageB = [&](int cb) {
    const char* src = (const char*)esp + (size_t)cb * (128 * EPAD * 2);
#pragma unroll
    for (int i = 0; i < 12; ++i) {
      __builtin_amdgcn_global_load_lds(
          (gcptr)(src + ((size_t)i * 256 + t) * 16),
          (lptr)((char*)B_s + ((size_t)i * 256 + w * 64) * 16), 16, 0, 0);
    }
    if (t < 128) {
      __builtin_amdgcn_global_load_lds(
          (gcptr)(src + ((size_t)12 * 256 + t) * 16),
          (lptr)((char*)B_s + ((size_t)12 * 256 + w * 64) * 16), 16, 0, 0);
    }
  };

  stageB(0);
  __syncthreads();   // drains ds_writes (A) and global_load_lds (B chunk 0)

  // A fragments, held in registers for the whole block (4 row-tiles x 6 K-steps)
  bf16x8 af[4][6];
#pragma unroll
  for (int rt = 0; rt < 4; ++rt)
#pragma unroll
    for (int s = 0; s < 6; ++s)
      af[rt][s] = *(const bf16x8*)(A_s + (rt * 16 + l15) * EPAD + s * 32 + g4 * 8);

  // prefetch this lane's 16 code norms: col(cb,ct) = (cb*8 + w*2 + ct)*16 + l15
  float nkreg[16];
#pragma unroll
  for (int cb8 = 0; cb8 < 8; ++cb8)
#pragma unroll
    for (int ct = 0; ct < 2; ++ct)
      nkreg[cb8 * 2 + ct] = norms[(cb8 * 8 + w * 2 + ct) * 16 + l15];

  float m1[16], m2[16]; int k1[16];
#pragma unroll
  for (int i = 0; i < 16; ++i) { m1[i] = INFINITY; m2[i] = INFINITY; k1[i] = 0; }

  f32x4 acc[4][2];

#pragma unroll
  for (int cb = 0; cb < 8; ++cb) {
#pragma unroll
    for (int rt = 0; rt < 4; ++rt)
#pragma unroll
      for (int ct = 0; ct < 2; ++ct)
        acc[rt][ct] = (f32x4){0.0f, 0.0f, 0.0f, 0.0f};

#pragma unroll
    for (int s = 0; s < 6; ++s) {
#pragma unroll
      for (int ct = 0; ct < 2; ++ct) {
        const bf16x8 bf =
            *(const bf16x8*)(B_s + (w * 32 + ct * 16 + l15) * EPAD + s * 32 + g4 * 8);
#pragma unroll
        for (int rt = 0; rt < 4; ++rt)
          acc[rt][ct] = __builtin_amdgcn_mfma_f32_16x16x32_bf16(
              af[rt][s], bf, acc[rt][ct], 0, 0, 0);
      }
    }

    __syncthreads();                 // all waves done reading B_s for this chunk
    if (cb < 7) stageB(cb + 1);      // issue next chunk's loads (latency hidden by epilogue)

    // epilogue: g~ = nk - 2*dot~ ; two-smallest + first-argmin tracking (k ascending)
#pragma unroll
    for (int ct = 0; ct < 2; ++ct) {
      const float nk = nkreg[cb * 2 + ct];
      const int   kv = (cb * 8 + w * 2 + ct) * 16 + l15;
#pragma unroll
      for (int rt = 0; rt < 4; ++rt) {
#pragma unroll
        for (int rg = 0; rg < 4; ++rg) {
          const float g  = fmaf(-2.0f, acc[rt][ct][rg], nk);
          const int   si = rt * 4 + rg;
          const bool  cnd = g < m1[si];
          m2[si] = fminf(m2[si], fmaxf(m1[si], g));   // second-smallest (old m1 if displaced)
          k1[si] = cnd ? kv : k1[si];
          m1[si] = fminf(m1[si], g);
        }
      }
    }
    __syncthreads();                 // next chunk's staging landed
  }

  // butterfly merge across the 16 col-lanes (same rows within each g4 group)
#pragma unroll
  for (int mask = 1; mask <= 8; mask <<= 1) {
#pragma unroll
    for (int si = 0; si < 16; ++si) {
      const float om1 = __shfl_xor(m1[si], mask, 64);
      const float om2 = __shfl_xor(m2[si], mask, 64);
      const int   ok1 = __shfl_xor(k1[si], mask, 64);
      const float big = fmaxf(m1[si], om1);
      m2[si] = fminf(fminf(m2[si], om2), big);
      if (om1 < m1[si]) k1[si] = ok1;    // exact ties -> flagged anyway (m2==m1)
      m1[si] = fminf(m1[si], om1);
    }
  }
  if (l15 == 0) {
#pragma unroll
    for (int rt = 0; rt < 4; ++rt)
#pragma unroll
      for (int rg = 0; rg < 4; ++rg) {
        const int row = rt * 16 + g4 * 4 + rg;
        red_m1[w][row] = m1[rt * 4 + rg];
        red_m2[w][row] = m2[rt * 4 + rg];
        red_k1[w][row] = k1[rt * 4 + rg];
      }
  }
  __syncthreads();
  if (t < 64) {
    float M1 = red_m1[0][t], M2 = red_m2[0][t]; int K1 = red_k1[0][t];
#pragma unroll
    for (int ww = 1; ww < 4; ++ww) {
      const float om1 = red_m1[ww][t], om2 = red_m2[ww][t]; const int ok1 = red_k1[ww][t];
      const float big = fmaxf(M1, om1);
      M2 = fminf(fminf(M2, om2), big);
      if (om1 < M1) K1 = ok1;
      M1 = fminf(M1, om1);
    }
    // gap > EPS  =>  K1 is provably the exact fp32 argmin; else flag for exact rescan
    out_idx[n0 + t] = (M2 - M1 <= EPS_THR) ? -1.0f : (float)K1;
  }
}

// Pass 2b: exact rescan of flagged rows (bit-exact reference semantics, first-min).
__global__ void vq_rescan(const float* __restrict__ xin, const float* __restrict__ emb,
                          const float* __restrict__ norms, float* __restrict__ out_idx)
{
  __shared__ float x_s[CDIM];
  __shared__ float flg[32];
  __shared__ float dred[256];
  __shared__ int   kred[256];
  const int t  = threadIdx.x;
  const int n0 = blockIdx.x * 32;
  if (t < 32) flg[t] = out_idx[n0 + t];
  __syncthreads();
  for (int i = 0; i < 32; ++i) {
    if (flg[i] >= 0.0f) continue;            // uniform branch (shared value)
    const int n = n0 + i;
    const int bb = n >> 10, hw = n & (HW - 1);
    if (t < 64) x_s[t] = xin[(size_t)bb * (CDIM * HW) + (size_t)t * HW + hw];
    __syncthreads();
    const float S = np_sumsq64(x_s);
    float dmin = INFINITY; int kmin = 0;
#pragma unroll
    for (int j = 0; j < 4; ++j) {
      const int k = t * 4 + j;               // ascending k per thread
      const float4* e4 = (const float4*)(emb + (size_t)k * CDIM);
      float d = 0.0f;
#pragma unroll
      for (int c4 = 0; c4 < 16; ++c4) {      // exact same chain as reference kernel
        const float4 a = e4[c4];
        d = fmaf(x_s[4*c4+0], a.x, d);
        d = fmaf(x_s[4*c4+1], a.y, d);
        d = fmaf(x_s[4*c4+2], a.z, d);
        d = fmaf(x_s[4*c4+3], a.w, d);
      }
      const float q = (S - 2.0f * d) + norms[k];
      if (q < dmin) { dmin = q; kmin = k; }
    }
    dred[t] = dmin; kred[t] = kmin;
    __syncthreads();
    for (int s = 128; s > 0; s >>= 1) {      // lexicographic (d,k) first-min
      if (t < s) {
        const float db = dred[t + s]; const int kb = kred[t + s];
        if (db < dred[t] || (db == dred[t] && kb < kred[t])) { dred[t] = db; kred[t] = kb; }
      }
      __syncthreads();
    }
    if (t == 0) out_idx[n] = (float)kred[0];
    __syncthreads();
  }
}

// Pass 2a: epilogue for ALL rows — identical arithmetic & partials structure to the
// previously-passing kernel (1024 blocks x 64 rows, same shfl reduce order).
__global__ __launch_bounds__(64)
void vq_epilogue(const float* __restrict__ xin, const float* __restrict__ emb,
                 const float* __restrict__ out_idx, float* __restrict__ out0,
                 double* __restrict__ partials, unsigned int* __restrict__ counts)
{
  __shared__ unsigned int hist_s[NUM_K];
  const int t = threadIdx.x;
  const int n = blockIdx.x * 64 + t;
  for (int i = t; i < NUM_K; i += 64) hist_s[i] = 0;
  __syncthreads();
  const int bb = n >> 10, hw = n & (HW - 1);
  const float* xb = xin + (size_t)bb * (CDIM * HW) + hw;
  int kmin = (int)out_idx[n];
  if (kmin < 0) kmin = 0;                     // safety clamp (should not happen)
  atomicAdd(&hist_s[kmin], 1u);
  const float4* eb = (const float4*)(emb + (size_t)kmin * CDIM);
  float4* o = (float4*)(out0 + (size_t)n * CDIM);
  float ssq = 0.0f;
#pragma unroll
  for (int c4 = 0; c4 < 16; ++c4) {
    const float4 q4 = eb[c4];
    const float x0 = xb[(4*c4+0) * HW], x1 = xb[(4*c4+1) * HW];
    const float x2 = xb[(4*c4+2) * HW], x3 = xb[(4*c4+3) * HW];
    const float u0 = q4.x - x0, u1 = q4.y - x1, u2 = q4.z - x2, u3 = q4.w - x3;
    ssq = fmaf(u0, u0, fmaf(u1, u1, fmaf(u2, u2, fmaf(u3, u3, ssq))));
    o[c4] = make_float4(x0 + u0, x1 + u1, x2 + u2, x3 + u3);
  }
#pragma unroll
  for (int off = 32; off > 0; off >>= 1) ssq += __shfl_down(ssq, off, 64);
  if (t == 0) partials[blockIdx.x] = (double)ssq;   // deterministic, no FP atomics
  __syncthreads();
  for (int i = t; i < NUM_K; i += 64) {
    const unsigned int v = hist_s[i];
    if (v) atomicAdd(&counts[i], v);
  }
}

__global__ void vq_final(const double* __restrict__ partials,
                         const unsigned int* __restrict__ counts,
                         float* __restrict__ out_loss, float* __restrict__ out_perp)
{
  __shared__ double sh[256];
  const int t = threadIdx.x;
  double acc = 0.0, ent = 0.0;
  for (int i = t; i < NBLK; i += 256) acc += partials[i];
  for (int k = t; k < NUM_K; k += 256) {
    const double pr = (double)counts[k] * (1.0 / 65536.0);
    ent += pr * log(pr + 1e-10);
  }
  sh[t] = acc;
  __syncthreads();
  for (int s = 128; s > 0; s >>= 1) { if (t < s) sh[t] += sh[t + s]; __syncthreads(); }
  const double total = sh[0];
  __syncthreads();
  sh[t] = ent;
  __syncthreads();
  for (int s = 128; s > 0; s >>= 1) { if (t < s) sh[t] += sh[t + s]; __syncthreads(); }
  if (t == 0) {
    out_loss[0] = (float)(1.25 * total / 4194304.0);
    out_perp[0] = (float)exp(-sh[0]);
  }
}

extern "C" void kernel_launch(void* const* d_in, const int* in_sizes, int n_in,
                              void* d_out, int out_size, void* d_ws, size_t ws_size,
                              hipStream_t stream)
{
  const float* xin = (const float*)d_in[0];
  const float* emb = (const float*)d_in[1];
  float* out = (float*)d_out;

  // ws layout: [0,4K) fp32 norms[1024] | [4K,8K) u32 counts[1024] | [8K,16K) f64 partials[1024]
  float*        norms    = (float*)d_ws;
  unsigned int* counts   = (unsigned int*)((char*)d_ws + 4096);
  double*       partials = (double*)((char*)d_ws + 8192);

  float* out0     = out;                       // 4194304 elements (BHWC flat)
  float* out_loss = out + 4194304;             // scalar
  float* out_idx  = out + 4194305;             // 65536 elements (as float)
  float* out_perp = out + 4194305 + 65536;     // scalar

  // split codebook e' (1024 x 200 bf16 = 400 KB) stashed in out0's head;
  // consumed by vq_dist, then fully overwritten by vq_epilogue.
  unsigned short* esp = (unsigned short*)out0;

  hipMemsetAsync((char*)d_ws + 4096, 0, 4096, stream);  // zero counts only

  vq_prep    <<<dim3(4),    dim3(256), 0, stream>>>(emb, norms, esp);
  vq_dist    <<<dim3(1024), dim3(256), 0, stream>>>(xin, norms, esp, out_idx);
  vq_rescan  <<<dim3(2048), dim3(256), 0, stream>>>(xin, emb, norms, out_idx);
  vq_epilogue<<<dim3(1024), dim3(64),  0, stream>>>(xin, emb, out_idx, out0, partials, counts);
  vq_final   <<<dim3(1),    dim3(256), 0, stream>>>(partials, counts, out_loss, out_perp);
}

// Round 2
// 368.141 us; speedup vs baseline: 1.5265x; 1.5265x over previous
//
#include <hip/hip_runtime.h>
#include <math.h>

#define NUM_K   1024
#define CDIM    64
#define HW      1024          // 32*32
#define NROWS   65536         // 64*1024
#define NBLK    1024          // epilogue blocks (64 rows each)
#define APAD    200           // A_s row stride in bf16 elems (400 B = 25*16B, odd -> bank-balanced)
#define BPAD    224           // esp row stride in bf16 elems (448 B, 64B-aligned fragments)
#define EPS_THR 1.25e-4f      // candidate threshold on packed g~ (incl. pack granularity)

using bf16x8 = __attribute__((ext_vector_type(8))) short;
using f32x4  = __attribute__((ext_vector_type(4))) float;

// numpy pairwise_sum order for n=64 contiguous fp32 (8 stride-8 chains,
// ((r0+r1)+(r2+r3))+((r4+r5)+(r6+r7))), squares rounded separately (no FMA).
__device__ __forceinline__ float np_sumsq64(const float* a) {
#pragma clang fp contract(off)
  float r0 = a[0]*a[0], r1 = a[1]*a[1], r2 = a[2]*a[2], r3 = a[3]*a[3];
  float r4 = a[4]*a[4], r5 = a[5]*a[5], r6 = a[6]*a[6], r7 = a[7]*a[7];
#pragma unroll
  for (int i = 8; i < 64; i += 8) {
    r0 += a[i+0]*a[i+0]; r1 += a[i+1]*a[i+1];
    r2 += a[i+2]*a[i+2]; r3 += a[i+3]*a[i+3];
    r4 += a[i+4]*a[i+4]; r5 += a[i+5]*a[i+5];
    r6 += a[i+6]*a[i+6]; r7 += a[i+7]*a[i+7];
  }
  return ((r0+r1)+(r2+r3))+((r4+r5)+(r6+r7));
}

// Pass 0: exact norms + split codebook e' = [e_hi | e_hi | e_lo] (bf16 trunc split),
// padded to BPAD (448B rows -> 64B-aligned fragments for coalesced L2 reads).
__global__ void vq_prep(const float* __restrict__ emb, float* __restrict__ norms,
                        unsigned short* __restrict__ esp)
{
  const int k = blockIdx.x * blockDim.x + threadIdx.x;
  if (k >= NUM_K) return;
  norms[k] = np_sumsq64(emb + k * CDIM);
  unsigned short* row = esp + (size_t)k * BPAD;
  for (int c = 0; c < CDIM; ++c) {
    const float v = emb[k * CDIM + c];
    const unsigned int vb = __float_as_uint(v);
    const unsigned short h = (unsigned short)(vb >> 16);           // bf16 trunc
    const float res = v - __uint_as_float((unsigned int)h << 16);
    const unsigned short l = (unsigned short)(__float_as_uint(res) >> 16);
    row[c] = h; row[64 + c] = h; row[128 + c] = l;
  }
  for (int i = 192; i < BPAD; ++i) row[i] = 0;
}

// Pass 1: split-bf16 MFMA distance filter, register-tight version.
//  - A (x rows, split [hi|lo|hi]) staged once in LDS; fragments RE-READ per K-step
//    (no persistent af[4][6] -> no spills).
//  - B (codes, split [hi|hi|lo]) read straight from L2 (all blocks share 448 KB).
//  - argmin index PACKED into low 10 mantissa bits of g~; min-tracking = plain fminf
//    (monotone); pack granularity + ref rounding + split error < EPS_THR.
// C layout: col=lane&15, row=(lane>>4)*4+reg [HW-verified, absmax 0 in r1].
__global__ __launch_bounds__(256, 3)
void vq_dist(const float* __restrict__ xin, const float* __restrict__ norms,
             const unsigned short* __restrict__ esp, float* __restrict__ out_idx)
{
  __shared__ __align__(16) unsigned short A_s[64 * APAD];   // 25600 B
  __shared__ float red_m1[4][64];
  __shared__ float red_m2[4][64];

  const int t    = threadIdx.x;
  const int lane = t & 63;
  const int w    = t >> 6;        // wave id = 32-col slice of each 128-col chunk
  const int l15  = lane & 15;
  const int g4   = lane >> 4;

  const int n0  = blockIdx.x * 64;
  const int b   = n0 >> 10;
  const int hw0 = n0 & (HW - 1);

  // ---- stage A: load x (coalesced across rows), trunc-split, pack [hi|lo|hi] ----
  {
    const int r = t & 63, q = t >> 6;             // row, 16-channel quarter
    const float* xb = xin + (size_t)b * (CDIM * HW) + hw0 + r;
    unsigned short* arow = A_s + r * APAD;
#pragma unroll
    for (int u = 0; u < 8; ++u) {
      const int c0 = q * 16 + 2 * u;
      const float v0 = xb[(size_t)c0 * HW];
      const float v1 = xb[(size_t)(c0 + 1) * HW];
      const unsigned int h0 = __float_as_uint(v0) >> 16;
      const unsigned int h1 = __float_as_uint(v1) >> 16;
      const float r0 = v0 - __uint_as_float(h0 << 16);
      const float r1 = v1 - __uint_as_float(h1 << 16);
      const unsigned int lo0 = __float_as_uint(r0) >> 16;
      const unsigned int lo1 = __float_as_uint(r1) >> 16;
      const unsigned int hh = h0 | (h1 << 16);
      const unsigned int ll = lo0 | (lo1 << 16);
      *(unsigned int*)(arow + c0)        = hh;   // slots [0,64):   x_hi
      *(unsigned int*)(arow + 64 + c0)   = ll;   // slots [64,128): x_lo
      *(unsigned int*)(arow + 128 + c0)  = hh;   // slots [128,192):x_hi
    }
  }
  __syncthreads();

  float m1[16], m2[16];
#pragma unroll
  for (int i = 0; i < 16; ++i) { m1[i] = INFINITY; m2[i] = INFINITY; }

  // per-lane A fragment base (bf16 elems); rt adds 16*APAD, s adds 32
  const unsigned short* aF = A_s + l15 * APAD + g4 * 8;
  // per-lane B pointers for (ct0, ct1); s adds 32, chunk adds 128*BPAD
  const unsigned short* pB = esp + (size_t)(w * 32 + l15) * BPAD + g4 * 8;
  const float* pN = norms + w * 32 + l15;

  // preloaded s=0 fragments of the current chunk (carried across iterations;
  // last iteration's extra preload reads harmless in-bounds garbage past esp)
  bf16x8 c0 = *(const bf16x8*)(pB);
  bf16x8 c1 = *(const bf16x8*)(pB + 16 * BPAD);

#pragma unroll 1
  for (int cb = 0; cb < 8; ++cb) {
    const float nk0 = pN[0];
    const float nk1 = pN[16];

    f32x4 acc[4][2];
#pragma unroll
    for (int rt = 0; rt < 4; ++rt)
#pragma unroll
      for (int ct = 0; ct < 2; ++ct)
        acc[rt][ct] = (f32x4){0.0f, 0.0f, 0.0f, 0.0f};

    // s = 0 uses the preloaded pair
    {
      const bf16x8 a0 = *(const bf16x8*)(aF);
      const bf16x8 a1 = *(const bf16x8*)(aF + 16 * APAD);
      const bf16x8 a2 = *(const bf16x8*)(aF + 32 * APAD);
      const bf16x8 a3 = *(const bf16x8*)(aF + 48 * APAD);
      acc[0][0] = __builtin_amdgcn_mfma_f32_16x16x32_bf16(a0, c0, acc[0][0], 0, 0, 0);
      acc[1][0] = __builtin_amdgcn_mfma_f32_16x16x32_bf16(a1, c0, acc[1][0], 0, 0, 0);
      acc[2][0] = __builtin_amdgcn_mfma_f32_16x16x32_bf16(a2, c0, acc[2][0], 0, 0, 0);
      acc[3][0] = __builtin_amdgcn_mfma_f32_16x16x32_bf16(a3, c0, acc[3][0], 0, 0, 0);
      acc[0][1] = __builtin_amdgcn_mfma_f32_16x16x32_bf16(a0, c1, acc[0][1], 0, 0, 0);
      acc[1][1] = __builtin_amdgcn_mfma_f32_16x16x32_bf16(a1, c1, acc[1][1], 0, 0, 0);
      acc[2][1] = __builtin_amdgcn_mfma_f32_16x16x32_bf16(a2, c1, acc[2][1], 0, 0, 0);
      acc[3][1] = __builtin_amdgcn_mfma_f32_16x16x32_bf16(a3, c1, acc[3][1], 0, 0, 0);
    }
#pragma unroll
    for (int s = 1; s < 6; ++s) {
      const bf16x8 b0 = *(const bf16x8*)(pB + s * 32);
      const bf16x8 b1 = *(const bf16x8*)(pB + 16 * BPAD + s * 32);
      const bf16x8 a0 = *(const bf16x8*)(aF + s * 32);
      const bf16x8 a1 = *(const bf16x8*)(aF + 16 * APAD + s * 32);
      const bf16x8 a2 = *(const bf16x8*)(aF + 32 * APAD + s * 32);
      const bf16x8 a3 = *(const bf16x8*)(aF + 48 * APAD + s * 32);
      acc[0][0] = __builtin_amdgcn_mfma_f32_16x16x32_bf16(a0, b0, acc[0][0], 0, 0, 0);
      acc[1][0] = __builtin_amdgcn_mfma_f32_16x16x32_bf16(a1, b0, acc[1][0], 0, 0, 0);
      acc[2][0] = __builtin_amdgcn_mfma_f32_16x16x32_bf16(a2, b0, acc[2][0], 0, 0, 0);
      acc[3][0] = __builtin_amdgcn_mfma_f32_16x16x32_bf16(a3, b0, acc[3][0], 0, 0, 0);
      acc[0][1] = __builtin_amdgcn_mfma_f32_16x16x32_bf16(a0, b1, acc[0][1], 0, 0, 0);
      acc[1][1] = __builtin_amdgcn_mfma_f32_16x16x32_bf16(a1, b1, acc[1][1], 0, 0, 0);
      acc[2][1] = __builtin_amdgcn_mfma_f32_16x16x32_bf16(a2, b1, acc[2][1], 0, 0, 0);
      acc[3][1] = __builtin_amdgcn_mfma_f32_16x16x32_bf16(a3, b1, acc[3][1], 0, 0, 0);
    }

    const unsigned kbase = (unsigned)(cb * 128 + w * 32 + l15);
    pB += 128 * BPAD;
    pN += 128;
    // preload next chunk's s=0 pair; hides L2 latency under the epilogue VALU
    c0 = *(const bf16x8*)(pB);
    c1 = *(const bf16x8*)(pB + 16 * BPAD);

    // epilogue: g~ = nk - 2*dot~, pack col idx into low 10 mantissa bits, fminf-track.
    // pack keeps ordering (monotone); within-granularity confusion (<=3e-5) is
    // strictly inside the EPS flag band -> resolved by exact rescan.
#pragma unroll
    for (int ct = 0; ct < 2; ++ct) {
      const float nk = ct ? nk1 : nk0;
      const unsigned kcol = kbase + (unsigned)(ct * 16);
#pragma unroll
      for (int rt = 0; rt < 4; ++rt) {
#pragma unroll
        for (int rg = 0; rg < 4; ++rg) {
          const float g  = fmaf(-2.0f, acc[rt][ct][rg], nk);
          const float gp = __uint_as_float((__float_as_uint(g) & 0xFFFFFC00u) | kcol);
          const int   si = rt * 4 + rg;
          m2[si] = fminf(m2[si], fmaxf(m1[si], gp));
          m1[si] = fminf(m1[si], gp);
        }
      }
    }
  }

  // butterfly merge across the 16 col-lanes (packed: no index shuffles needed)
#pragma unroll
  for (int mask = 1; mask <= 8; mask <<= 1) {
#pragma unroll
    for (int si = 0; si < 16; ++si) {
      const float om1 = __shfl_xor(m1[si], mask, 64);
      const float om2 = __shfl_xor(m2[si], mask, 64);
      m2[si] = fminf(fminf(m2[si], om2), fmaxf(m1[si], om1));
      m1[si] = fminf(m1[si], om1);
    }
  }
  if (l15 == 0) {
#pragma unroll
    for (int rt = 0; rt < 4; ++rt)
#pragma unroll
      for (int rg = 0; rg < 4; ++rg) {
        const int row = rt * 16 + g4 * 4 + rg;
        red_m1[w][row] = m1[rt * 4 + rg];
        red_m2[w][row] = m2[rt * 4 + rg];
      }
  }
  __syncthreads();
  if (t < 64) {
    float M1 = red_m1[0][t], M2 = red_m2[0][t];
#pragma unroll
    for (int ww = 1; ww < 4; ++ww) {
      const float om1 = red_m1[ww][t], om2 = red_m2[ww][t];
      M2 = fminf(fminf(M2, om2), fmaxf(M1, om1));
      M1 = fminf(M1, om1);
    }
    const int K1 = (int)(__float_as_uint(M1) & 1023u);
    // gap > EPS => K1 provably the exact fp32 argmin; else flag for exact rescan
    out_idx[n0 + t] = (M2 - M1 <= EPS_THR) ? -1.0f : (float)K1;
  }
}

// Pass 2b: exact rescan of flagged rows (bit-exact reference semantics, first-min).
__global__ void vq_rescan(const float* __restrict__ xin, const float* __restrict__ emb,
                          const float* __restrict__ norms, float* __restrict__ out_idx)
{
  __shared__ float x_s[CDIM];
  __shared__ float flg[32];
  __shared__ float dred[256];
  __shared__ int   kred[256];
  const int t  = threadIdx.x;
  const int n0 = blockIdx.x * 32;
  if (t < 32) flg[t] = out_idx[n0 + t];
  __syncthreads();
  for (int i = 0; i < 32; ++i) {
    if (flg[i] >= 0.0f) continue;            // uniform branch (shared value)
    const int n = n0 + i;
    const int bb = n >> 10, hw = n & (HW - 1);
    if (t < 64) x_s[t] = xin[(size_t)bb * (CDIM * HW) + (size_t)t * HW + hw];
    __syncthreads();
    const float S = np_sumsq64(x_s);
    float dmin = INFINITY; int kmin = 0;
#pragma unroll
    for (int j = 0; j < 4; ++j) {
      const int k = t * 4 + j;               // ascending k per thread
      const float4* e4 = (const float4*)(emb + (size_t)k * CDIM);
      float d = 0.0f;
#pragma unroll
      for (int c4 = 0; c4 < 16; ++c4) {      // exact same chain as reference kernel
        const float4 a = e4[c4];
        d = fmaf(x_s[4*c4+0], a.x, d);
        d = fmaf(x_s[4*c4+1], a.y, d);
        d = fmaf(x_s[4*c4+2], a.z, d);
        d = fmaf(x_s[4*c4+3], a.w, d);
      }
      const float q = (S - 2.0f * d) + norms[k];
      if (q < dmin) { dmin = q; kmin = k; }
    }
    dred[t] = dmin; kred[t] = kmin;
    __syncthreads();
    for (int s = 128; s > 0; s >>= 1) {      // lexicographic (d,k) first-min
      if (t < s) {
        const float db = dred[t + s]; const int kb = kred[t + s];
        if (db < dred[t] || (db == dred[t] && kb < kred[t])) { dred[t] = db; kred[t] = kb; }
      }
      __syncthreads();
    }
    if (t == 0) out_idx[n] = (float)kred[0];
    __syncthreads();
  }
}

// Pass 2a: epilogue for ALL rows — identical arithmetic & partials structure to the
// previously-passing kernel (1024 blocks x 64 rows, same shfl reduce order).
__global__ __launch_bounds__(64)
void vq_epilogue(const float* __restrict__ xin, const float* __restrict__ emb,
                 const float* __restrict__ out_idx, float* __restrict__ out0,
                 double* __restrict__ partials, unsigned int* __restrict__ counts)
{
  __shared__ unsigned int hist_s[NUM_K];
  const int t = threadIdx.x;
  const int n = blockIdx.x * 64 + t;
  for (int i = t; i < NUM_K; i += 64) hist_s[i] = 0;
  __syncthreads();
  const int bb = n >> 10, hw = n & (HW - 1);
  const float* xb = xin + (size_t)bb * (CDIM * HW) + hw;
  int kmin = (int)out_idx[n];
  if (kmin < 0) kmin = 0;                     // safety clamp (should not happen)
  atomicAdd(&hist_s[kmin], 1u);
  const float4* eb = (const float4*)(emb + (size_t)kmin * CDIM);
  float4* o = (float4*)(out0 + (size_t)n * CDIM);
  float ssq = 0.0f;
#pragma unroll
  for (int c4 = 0; c4 < 16; ++c4) {
    const float4 q4 = eb[c4];
    const float x0 = xb[(4*c4+0) * HW], x1 = xb[(4*c4+1) * HW];
    const float x2 = xb[(4*c4+2) * HW], x3 = xb[(4*c4+3) * HW];
    const float u0 = q4.x - x0, u1 = q4.y - x1, u2 = q4.z - x2, u3 = q4.w - x3;
    ssq = fmaf(u0, u0, fmaf(u1, u1, fmaf(u2, u2, fmaf(u3, u3, ssq))));
    o[c4] = make_float4(x0 + u0, x1 + u1, x2 + u2, x3 + u3);
  }
#pragma unroll
  for (int off = 32; off > 0; off >>= 1) ssq += __shfl_down(ssq, off, 64);
  if (t == 0) partials[blockIdx.x] = (double)ssq;   // deterministic, no FP atomics
  __syncthreads();
  for (int i = t; i < NUM_K; i += 64) {
    const unsigned int v = hist_s[i];
    if (v) atomicAdd(&counts[i], v);
  }
}

__global__ void vq_final(const double* __restrict__ partials,
                         const unsigned int* __restrict__ counts,
                         float* __restrict__ out_loss, float* __restrict__ out_perp)
{
  __shared__ double sh[256];
  const int t = threadIdx.x;
  double acc = 0.0, ent = 0.0;
  for (int i = t; i < NBLK; i += 256) acc += partials[i];
  for (int k = t; k < NUM_K; k += 256) {
    const double pr = (double)counts[k] * (1.0 / 65536.0);
    ent += pr * log(pr + 1e-10);
  }
  sh[t] = acc;
  __syncthreads();
  for (int s = 128; s > 0; s >>= 1) { if (t < s) sh[t] += sh[t + s]; __syncthreads(); }
  const double total = sh[0];
  __syncthreads();
  sh[t] = ent;
  __syncthreads();
  for (int s = 128; s > 0; s >>= 1) { if (t < s) sh[t] += sh[t + s]; __syncthreads(); }
  if (t == 0) {
    out_loss[0] = (float)(1.25 * total / 4194304.0);
    out_perp[0] = (float)exp(-sh[0]);
  }
}

extern "C" void kernel_launch(void* const* d_in, const int* in_sizes, int n_in,
                              void* d_out, int out_size, void* d_ws, size_t ws_size,
                              hipStream_t stream)
{
  const float* xin = (const float*)d_in[0];
  const float* emb = (const float*)d_in[1];
  float* out = (float*)d_out;

  // ws layout: [0,4K) fp32 norms[1024] | [4K,8K) u32 counts[1024] | [8K,16K) f64 partials[1024]
  float*        norms    = (float*)d_ws;
  unsigned int* counts   = (unsigned int*)((char*)d_ws + 4096);
  double*       partials = (double*)((char*)d_ws + 8192);

  float* out0     = out;                       // 4194304 elements (BHWC flat)
  float* out_loss = out + 4194304;             // scalar
  float* out_idx  = out + 4194305;             // 65536 elements (as float)
  float* out_perp = out + 4194305 + 65536;     // scalar

  // split codebook e' (1024 x 224 bf16 = 448 KB) stashed in out0's head;
  // consumed by vq_dist (straight from L2), then fully overwritten by vq_epilogue.
  unsigned short* esp = (unsigned short*)out0;

  hipMemsetAsync((char*)d_ws + 4096, 0, 4096, stream);  // zero counts only

  vq_prep    <<<dim3(16),   dim3(64),  0, stream>>>(emb, norms, esp);
  vq_dist    <<<dim3(1024), dim3(256), 0, stream>>>(xin, norms, esp, out_idx);
  vq_rescan  <<<dim3(2048), dim3(256), 0, stream>>>(xin, emb, norms, out_idx);
  vq_epilogue<<<dim3(1024), dim3(64),  0, stream>>>(xin, emb, out_idx, out0, partials, counts);
  vq_final   <<<dim3(1),    dim3(256), 0, stream>>>(partials, counts, out_loss, out_perp);
}

// Round 3
// 298.974 us; speedup vs baseline: 1.8797x; 1.2313x over previous
//
#include <hip/hip_runtime.h>
#include <math.h>

#define NUM_K   1024
#define CDIM    64
#define HW      1024          // 32*32
#define NROWS   65536         // 64*1024
#define NBLK    1024          // epilogue blocks (64 rows each)
#define APAD    200           // A_s row stride in bf16 elems (400 B = 25*16B, odd -> bank-balanced)
#define BPAD    224           // esp row stride in bf16 elems (448 B, 64B-aligned fragments)
#define EPS_THR 1.25e-4f      // candidate threshold on packed g~ (incl. pack granularity)

using bf16x8 = __attribute__((ext_vector_type(8))) short;
using f32x4  = __attribute__((ext_vector_type(4))) float;

// numpy pairwise_sum order for n=64 contiguous fp32 (8 stride-8 chains,
// ((r0+r1)+(r2+r3))+((r4+r5)+(r6+r7))), squares rounded separately (no FMA).
__device__ __forceinline__ float np_sumsq64(const float* a) {
#pragma clang fp contract(off)
  float r0 = a[0]*a[0], r1 = a[1]*a[1], r2 = a[2]*a[2], r3 = a[3]*a[3];
  float r4 = a[4]*a[4], r5 = a[5]*a[5], r6 = a[6]*a[6], r7 = a[7]*a[7];
#pragma unroll
  for (int i = 8; i < 64; i += 8) {
    r0 += a[i+0]*a[i+0]; r1 += a[i+1]*a[i+1];
    r2 += a[i+2]*a[i+2]; r3 += a[i+3]*a[i+3];
    r4 += a[i+4]*a[i+4]; r5 += a[i+5]*a[i+5];
    r6 += a[i+6]*a[i+6]; r7 += a[i+7]*a[i+7];
  }
  return ((r0+r1)+(r2+r3))+((r4+r5)+(r6+r7));
}

// Pass 0: exact norms + split codebook e' = [e_hi | e_hi | e_lo] (bf16 trunc split),
// padded to BPAD (448B rows -> 64B-aligned fragments for coalesced L2 reads).
__global__ void vq_prep(const float* __restrict__ emb, float* __restrict__ norms,
                        unsigned short* __restrict__ esp)
{
  const int k = blockIdx.x * blockDim.x + threadIdx.x;
  if (k >= NUM_K) return;
  norms[k] = np_sumsq64(emb + k * CDIM);
  unsigned short* row = esp + (size_t)k * BPAD;
  for (int c = 0; c < CDIM; ++c) {
    const float v = emb[k * CDIM + c];
    const unsigned int vb = __float_as_uint(v);
    const unsigned short h = (unsigned short)(vb >> 16);           // bf16 trunc
    const float res = v - __uint_as_float((unsigned int)h << 16);
    const unsigned short l = (unsigned short)(__float_as_uint(res) >> 16);
    row[c] = h; row[64 + c] = h; row[128 + c] = l;
  }
  for (int i = 192; i < BPAD; ++i) row[i] = 0;
}

// Pass 1: split-bf16 MFMA distance filter (validated in r1/r2, absmax 0).
// Adds: compact flag list (row ids with gap <= EPS) for the wave-parallel rescan.
__global__ __launch_bounds__(256, 3)
void vq_dist(const float* __restrict__ xin, const float* __restrict__ norms,
             const unsigned short* __restrict__ esp, float* __restrict__ out_idx,
             unsigned int* __restrict__ nflag, unsigned int* __restrict__ flaglist)
{
  __shared__ __align__(16) unsigned short A_s[64 * APAD];   // 25600 B
  __shared__ float red_m1[4][64];
  __shared__ float red_m2[4][64];

  const int t    = threadIdx.x;
  const int lane = t & 63;
  const int w    = t >> 6;        // wave id = 32-col slice of each 128-col chunk
  const int l15  = lane & 15;
  const int g4   = lane >> 4;

  const int n0  = blockIdx.x * 64;
  const int b   = n0 >> 10;
  const int hw0 = n0 & (HW - 1);

  // ---- stage A: load x (coalesced across rows), trunc-split, pack [hi|lo|hi] ----
  {
    const int r = t & 63, q = t >> 6;             // row, 16-channel quarter
    const float* xb = xin + (size_t)b * (CDIM * HW) + hw0 + r;
    unsigned short* arow = A_s + r * APAD;
#pragma unroll
    for (int u = 0; u < 8; ++u) {
      const int c0 = q * 16 + 2 * u;
      const float v0 = xb[(size_t)c0 * HW];
      const float v1 = xb[(size_t)(c0 + 1) * HW];
      const unsigned int h0 = __float_as_uint(v0) >> 16;
      const unsigned int h1 = __float_as_uint(v1) >> 16;
      const float r0 = v0 - __uint_as_float(h0 << 16);
      const float r1 = v1 - __uint_as_float(h1 << 16);
      const unsigned int lo0 = __float_as_uint(r0) >> 16;
      const unsigned int lo1 = __float_as_uint(r1) >> 16;
      const unsigned int hh = h0 | (h1 << 16);
      const unsigned int ll = lo0 | (lo1 << 16);
      *(unsigned int*)(arow + c0)        = hh;   // slots [0,64):   x_hi
      *(unsigned int*)(arow + 64 + c0)   = ll;   // slots [64,128): x_lo
      *(unsigned int*)(arow + 128 + c0)  = hh;   // slots [128,192):x_hi
    }
  }
  __syncthreads();

  float m1[16], m2[16];
#pragma unroll
  for (int i = 0; i < 16; ++i) { m1[i] = INFINITY; m2[i] = INFINITY; }

  // per-lane A fragment base (bf16 elems); rt adds 16*APAD, s adds 32
  const unsigned short* aF = A_s + l15 * APAD + g4 * 8;
  // per-lane B pointers for (ct0, ct1); s adds 32, chunk adds 128*BPAD
  const unsigned short* pB = esp + (size_t)(w * 32 + l15) * BPAD + g4 * 8;
  const float* pN = norms + w * 32 + l15;

  // preloaded s=0 fragments of the current chunk (carried across iterations;
  // last iteration's extra preload reads harmless in-bounds garbage past esp)
  bf16x8 c0 = *(const bf16x8*)(pB);
  bf16x8 c1 = *(const bf16x8*)(pB + 16 * BPAD);

#pragma unroll 1
  for (int cb = 0; cb < 8; ++cb) {
    const float nk0 = pN[0];
    const float nk1 = pN[16];

    f32x4 acc[4][2];
#pragma unroll
    for (int rt = 0; rt < 4; ++rt)
#pragma unroll
      for (int ct = 0; ct < 2; ++ct)
        acc[rt][ct] = (f32x4){0.0f, 0.0f, 0.0f, 0.0f};

    // s = 0 uses the preloaded pair
    {
      const bf16x8 a0 = *(const bf16x8*)(aF);
      const bf16x8 a1 = *(const bf16x8*)(aF + 16 * APAD);
      const bf16x8 a2 = *(const bf16x8*)(aF + 32 * APAD);
      const bf16x8 a3 = *(const bf16x8*)(aF + 48 * APAD);
      acc[0][0] = __builtin_amdgcn_mfma_f32_16x16x32_bf16(a0, c0, acc[0][0], 0, 0, 0);
      acc[1][0] = __builtin_amdgcn_mfma_f32_16x16x32_bf16(a1, c0, acc[1][0], 0, 0, 0);
      acc[2][0] = __builtin_amdgcn_mfma_f32_16x16x32_bf16(a2, c0, acc[2][0], 0, 0, 0);
      acc[3][0] = __builtin_amdgcn_mfma_f32_16x16x32_bf16(a3, c0, acc[3][0], 0, 0, 0);
      acc[0][1] = __builtin_amdgcn_mfma_f32_16x16x32_bf16(a0, c1, acc[0][1], 0, 0, 0);
      acc[1][1] = __builtin_amdgcn_mfma_f32_16x16x32_bf16(a1, c1, acc[1][1], 0, 0, 0);
      acc[2][1] = __builtin_amdgcn_mfma_f32_16x16x32_bf16(a2, c1, acc[2][1], 0, 0, 0);
      acc[3][1] = __builtin_amdgcn_mfma_f32_16x16x32_bf16(a3, c1, acc[3][1], 0, 0, 0);
    }
#pragma unroll
    for (int s = 1; s < 6; ++s) {
      const bf16x8 b0 = *(const bf16x8*)(pB + s * 32);
      const bf16x8 b1 = *(const bf16x8*)(pB + 16 * BPAD + s * 32);
      const bf16x8 a0 = *(const bf16x8*)(aF + s * 32);
      const bf16x8 a1 = *(const bf16x8*)(aF + 16 * APAD + s * 32);
      const bf16x8 a2 = *(const bf16x8*)(aF + 32 * APAD + s * 32);
      const bf16x8 a3 = *(const bf16x8*)(aF + 48 * APAD + s * 32);
      acc[0][0] = __builtin_amdgcn_mfma_f32_16x16x32_bf16(a0, b0, acc[0][0], 0, 0, 0);
      acc[1][0] = __builtin_amdgcn_mfma_f32_16x16x32_bf16(a1, b0, acc[1][0], 0, 0, 0);
      acc[2][0] = __builtin_amdgcn_mfma_f32_16x16x32_bf16(a2, b0, acc[2][0], 0, 0, 0);
      acc[3][0] = __builtin_amdgcn_mfma_f32_16x16x32_bf16(a3, b0, acc[3][0], 0, 0, 0);
      acc[0][1] = __builtin_amdgcn_mfma_f32_16x16x32_bf16(a0, b1, acc[0][1], 0, 0, 0);
      acc[1][1] = __builtin_amdgcn_mfma_f32_16x16x32_bf16(a1, b1, acc[1][1], 0, 0, 0);
      acc[2][1] = __builtin_amdgcn_mfma_f32_16x16x32_bf16(a2, b1, acc[2][1], 0, 0, 0);
      acc[3][1] = __builtin_amdgcn_mfma_f32_16x16x32_bf16(a3, b1, acc[3][1], 0, 0, 0);
    }

    const unsigned kbase = (unsigned)(cb * 128 + w * 32 + l15);
    pB += 128 * BPAD;
    pN += 128;
    // preload next chunk's s=0 pair; hides L2 latency under the epilogue VALU
    c0 = *(const bf16x8*)(pB);
    c1 = *(const bf16x8*)(pB + 16 * BPAD);

    // epilogue: g~ = nk - 2*dot~, pack col idx into low 10 mantissa bits, fminf-track.
#pragma unroll
    for (int ct = 0; ct < 2; ++ct) {
      const float nk = ct ? nk1 : nk0;
      const unsigned kcol = kbase + (unsigned)(ct * 16);
#pragma unroll
      for (int rt = 0; rt < 4; ++rt) {
#pragma unroll
        for (int rg = 0; rg < 4; ++rg) {
          const float g  = fmaf(-2.0f, acc[rt][ct][rg], nk);
          const float gp = __uint_as_float((__float_as_uint(g) & 0xFFFFFC00u) | kcol);
          const int   si = rt * 4 + rg;
          m2[si] = fminf(m2[si], fmaxf(m1[si], gp));
          m1[si] = fminf(m1[si], gp);
        }
      }
    }
  }

  // butterfly merge across the 16 col-lanes (packed: no index shuffles needed)
#pragma unroll
  for (int mask = 1; mask <= 8; mask <<= 1) {
#pragma unroll
    for (int si = 0; si < 16; ++si) {
      const float om1 = __shfl_xor(m1[si], mask, 64);
      const float om2 = __shfl_xor(m2[si], mask, 64);
      m2[si] = fminf(fminf(m2[si], om2), fmaxf(m1[si], om1));
      m1[si] = fminf(m1[si], om1);
    }
  }
  if (l15 == 0) {
#pragma unroll
    for (int rt = 0; rt < 4; ++rt)
#pragma unroll
      for (int rg = 0; rg < 4; ++rg) {
        const int row = rt * 16 + g4 * 4 + rg;
        red_m1[w][row] = m1[rt * 4 + rg];
        red_m2[w][row] = m2[rt * 4 + rg];
      }
  }
  __syncthreads();
  if (t < 64) {
    float M1 = red_m1[0][t], M2 = red_m2[0][t];
#pragma unroll
    for (int ww = 1; ww < 4; ++ww) {
      const float om1 = red_m1[ww][t], om2 = red_m2[ww][t];
      M2 = fminf(fminf(M2, om2), fmaxf(M1, om1));
      M1 = fminf(M1, om1);
    }
    const int K1 = (int)(__float_as_uint(M1) & 1023u);
    out_idx[n0 + t] = (float)K1;     // best guess; flagged rows fixed by rescan
    if (M2 - M1 <= EPS_THR) {        // gap too small -> exact rescan required
      const unsigned pos = atomicAdd(nflag, 1u);
      flaglist[pos] = (unsigned)(n0 + t);
    }
  }
}

// Pass 2b: exact rescan, wave-parallel over the compact flag list.
// One wave per flagged row: lane c loads x[c], full-vector broadcast via shfl,
// each lane scans 16 ascending codes with the bit-exact reference FMA chain,
// lexicographic (d,k) butterfly -> np first-min semantics.
__global__ __launch_bounds__(256)
void vq_rescan(const float* __restrict__ xin, const float* __restrict__ emb,
               const float* __restrict__ norms,
               const unsigned int* __restrict__ nflag,
               const unsigned int* __restrict__ flaglist,
               float* __restrict__ out_idx)
{
  const int t    = threadIdx.x;
  const int w    = t >> 6;
  const int lane = t & 63;
  const unsigned nf  = *nflag;
  const unsigned wid = blockIdx.x * 4 + w;
  const unsigned nw  = gridDim.x * 4;

  for (unsigned i = wid; i < nf; i += nw) {
    const int n  = (int)flaglist[i];
    const int bb = n >> 10, hw = n & (HW - 1);
    // lane c holds x[c]; broadcast to full per-lane vector
    const float xv = xin[(size_t)bb * (CDIM * HW) + (size_t)lane * HW + hw];
    float xr[CDIM];
#pragma unroll
    for (int c = 0; c < CDIM; ++c) xr[c] = __shfl(xv, c, 64);
    const float S = np_sumsq64(xr);

    float dmin = INFINITY; int kmin = 0;
#pragma unroll 2
    for (int j = 0; j < 16; ++j) {
      const int k = lane * 16 + j;             // ascending k per lane
      const float4* e4 = (const float4*)(emb + (size_t)k * CDIM);
      float d = 0.0f;
#pragma unroll
      for (int c4 = 0; c4 < 16; ++c4) {        // exact same chain as reference kernel
        const float4 a = e4[c4];
        d = fmaf(xr[4*c4+0], a.x, d);
        d = fmaf(xr[4*c4+1], a.y, d);
        d = fmaf(xr[4*c4+2], a.z, d);
        d = fmaf(xr[4*c4+3], a.w, d);
      }
      const float q = (S - 2.0f * d) + norms[k];
      if (q < dmin) { dmin = q; kmin = k; }    // strict < keeps first (lowest k)
    }
    // lexicographic (d,k) first-min across lanes
#pragma unroll
    for (int mask = 1; mask < 64; mask <<= 1) {
      const float od = __shfl_xor(dmin, mask, 64);
      const int   ok = __shfl_xor(kmin, mask, 64);
      if (od < dmin || (od == dmin && ok < kmin)) { dmin = od; kmin = ok; }
    }
    if (lane == 0) out_idx[n] = (float)kmin;
  }
}

// Pass 2a: epilogue for ALL rows — identical arithmetic & partials structure to the
// previously-passing kernel (1024 blocks x 64 rows, same shfl reduce order).
__global__ __launch_bounds__(64)
void vq_epilogue(const float* __restrict__ xin, const float* __restrict__ emb,
                 const float* __restrict__ out_idx, float* __restrict__ out0,
                 double* __restrict__ partials, unsigned int* __restrict__ counts)
{
  __shared__ unsigned int hist_s[NUM_K];
  const int t = threadIdx.x;
  const int n = blockIdx.x * 64 + t;
  for (int i = t; i < NUM_K; i += 64) hist_s[i] = 0;
  __syncthreads();
  const int bb = n >> 10, hw = n & (HW - 1);
  const float* xb = xin + (size_t)bb * (CDIM * HW) + hw;
  int kmin = (int)out_idx[n];
  if (kmin < 0) kmin = 0;                     // safety clamp (should not happen)
  atomicAdd(&hist_s[kmin], 1u);
  const float4* eb = (const float4*)(emb + (size_t)kmin * CDIM);
  float4* o = (float4*)(out0 + (size_t)n * CDIM);
  float ssq = 0.0f;
#pragma unroll
  for (int c4 = 0; c4 < 16; ++c4) {
    const float4 q4 = eb[c4];
    const float x0 = xb[(4*c4+0) * HW], x1 = xb[(4*c4+1) * HW];
    const float x2 = xb[(4*c4+2) * HW], x3 = xb[(4*c4+3) * HW];
    const float u0 = q4.x - x0, u1 = q4.y - x1, u2 = q4.z - x2, u3 = q4.w - x3;
    ssq = fmaf(u0, u0, fmaf(u1, u1, fmaf(u2, u2, fmaf(u3, u3, ssq))));
    o[c4] = make_float4(x0 + u0, x1 + u1, x2 + u2, x3 + u3);
  }
#pragma unroll
  for (int off = 32; off > 0; off >>= 1) ssq += __shfl_down(ssq, off, 64);
  if (t == 0) partials[blockIdx.x] = (double)ssq;   // deterministic, no FP atomics
  __syncthreads();
  for (int i = t; i < NUM_K; i += 64) {
    const unsigned int v = hist_s[i];
    if (v) atomicAdd(&counts[i], v);
  }
}

__global__ void vq_final(const double* __restrict__ partials,
                         const unsigned int* __restrict__ counts,
                         float* __restrict__ out_loss, float* __restrict__ out_perp)
{
  __shared__ double sh[256];
  const int t = threadIdx.x;
  double acc = 0.0, ent = 0.0;
  for (int i = t; i < NBLK; i += 256) acc += partials[i];
  for (int k = t; k < NUM_K; k += 256) {
    const double pr = (double)counts[k] * (1.0 / 65536.0);
    ent += pr * log(pr + 1e-10);
  }
  sh[t] = acc;
  __syncthreads();
  for (int s = 128; s > 0; s >>= 1) { if (t < s) sh[t] += sh[t + s]; __syncthreads(); }
  const double total = sh[0];
  __syncthreads();
  sh[t] = ent;
  __syncthreads();
  for (int s = 128; s > 0; s >>= 1) { if (t < s) sh[t] += sh[t + s]; __syncthreads(); }
  if (t == 0) {
    out_loss[0] = (float)(1.25 * total / 4194304.0);
    out_perp[0] = (float)exp(-sh[0]);
  }
}

extern "C" void kernel_launch(void* const* d_in, const int* in_sizes, int n_in,
                              void* d_out, int out_size, void* d_ws, size_t ws_size,
                              hipStream_t stream)
{
  const float* xin = (const float*)d_in[0];
  const float* emb = (const float*)d_in[1];
  float* out = (float*)d_out;

  // ws layout: [0,4K) fp32 norms[1024] | [4K,8K) u32 counts[1024] | [8K,16K) f64 partials[1024]
  float*        norms    = (float*)d_ws;
  unsigned int* counts   = (unsigned int*)((char*)d_ws + 4096);
  double*       partials = (double*)((char*)d_ws + 8192);

  float* out0     = out;                       // 4194304 elements (BHWC flat)
  float* out_loss = out + 4194304;             // scalar
  float* out_idx  = out + 4194305;             // 65536 elements (as float)
  float* out_perp = out + 4194305 + 65536;     // scalar

  // scratch stashed in out0 (consumed before vq_epilogue overwrites it):
  //   [0, 448K)           split codebook e' (1024 x 224 bf16)
  //   [8M, 8M+4)          u32 flag counter
  //   [8M+4, 8M+4+256K)   u32 flaglist (worst case 65536 rows)
  unsigned short* esp      = (unsigned short*)out0;
  unsigned int*   nflag    = (unsigned int*)((char*)out0 + (8u << 20));
  unsigned int*   flaglist = nflag + 1;

  hipMemsetAsync((char*)d_ws + 4096, 0, 4096, stream);  // zero counts
  hipMemsetAsync(nflag, 0, 4, stream);                  // zero flag counter

  vq_prep    <<<dim3(16),   dim3(64),  0, stream>>>(emb, norms, esp);
  vq_dist    <<<dim3(1024), dim3(256), 0, stream>>>(xin, norms, esp, out_idx,
                                                    nflag, flaglist);
  vq_rescan  <<<dim3(1024), dim3(256), 0, stream>>>(xin, emb, norms, nflag,
                                                    flaglist, out_idx);
  vq_epilogue<<<dim3(1024), dim3(64),  0, stream>>>(xin, emb, out_idx, out0, partials, counts);
  vq_final   <<<dim3(1),    dim3(256), 0, stream>>>(partials, counts, out_loss, out_perp);
}

// Round 4
// 208.183 us; speedup vs baseline: 2.6994x; 1.4361x over previous
//
#include <hip/hip_runtime.h>
#include <math.h>

#define NUM_K   1024
#define CDIM    64
#define HW      1024          // 32*32
#define NROWS   65536         // 64*1024
#define NBLK    1024          // epilogue blocks (64 rows each)
#define APAD    200           // A_s row stride in bf16 elems (400 B = 25*16B, odd -> bank-balanced)
#define BPAD    224           // esp row stride in bf16 elems (448 B, 64B-aligned fragments)
#define EPS_THR 1.25e-4f      // candidate threshold on packed g~ (incl. pack granularity)
#define RSROWS  16            // rescan rows per block
#define EPADR   68            // rescan LDS row pad (17 float4: 2-way read conflict = free)

using bf16x8 = __attribute__((ext_vector_type(8))) short;
using f32x4  = __attribute__((ext_vector_type(4))) float;

// numpy pairwise_sum order for n=64 contiguous fp32 (8 stride-8 chains,
// ((r0+r1)+(r2+r3))+((r4+r5)+(r6+r7))), squares rounded separately (no FMA).
__device__ __forceinline__ float np_sumsq64(const float* a) {
#pragma clang fp contract(off)
  float r0 = a[0]*a[0], r1 = a[1]*a[1], r2 = a[2]*a[2], r3 = a[3]*a[3];
  float r4 = a[4]*a[4], r5 = a[5]*a[5], r6 = a[6]*a[6], r7 = a[7]*a[7];
#pragma unroll
  for (int i = 8; i < 64; i += 8) {
    r0 += a[i+0]*a[i+0]; r1 += a[i+1]*a[i+1];
    r2 += a[i+2]*a[i+2]; r3 += a[i+3]*a[i+3];
    r4 += a[i+4]*a[i+4]; r5 += a[i+5]*a[i+5];
    r6 += a[i+6]*a[i+6]; r7 += a[i+7]*a[i+7];
  }
  return ((r0+r1)+(r2+r3))+((r4+r5)+(r6+r7));
}

// Pass 0: exact norms + split codebook e' = [e_hi | e_hi | e_lo] (bf16 trunc split).
__global__ void vq_prep(const float* __restrict__ emb, float* __restrict__ norms,
                        unsigned short* __restrict__ esp)
{
  const int k = blockIdx.x * blockDim.x + threadIdx.x;
  if (k >= NUM_K) return;
  norms[k] = np_sumsq64(emb + k * CDIM);
  unsigned short* row = esp + (size_t)k * BPAD;
  for (int c = 0; c < CDIM; ++c) {
    const float v = emb[k * CDIM + c];
    const unsigned int vb = __float_as_uint(v);
    const unsigned short h = (unsigned short)(vb >> 16);           // bf16 trunc
    const float res = v - __uint_as_float((unsigned int)h << 16);
    const unsigned short l = (unsigned short)(__float_as_uint(res) >> 16);
    row[c] = h; row[64 + c] = h; row[128 + c] = l;
  }
  for (int i = 192; i < BPAD; ++i) row[i] = 0;
}

// Pass 1: split-bf16 MFMA distance filter (validated r1-r3, absmax 0).
// r4 change: __launch_bounds__(256,3)->(256,2). At the 128-VGPR cap the scheduler
// had ~0 headroom to hoist the 12 per-chunk L2 B-loads; 256-cap lets it pipeline.
__global__ __launch_bounds__(256, 2)
void vq_dist(const float* __restrict__ xin, const float* __restrict__ norms,
             const unsigned short* __restrict__ esp, float* __restrict__ out_idx,
             unsigned int* __restrict__ nflag, unsigned int* __restrict__ flaglist)
{
  __shared__ __align__(16) unsigned short A_s[64 * APAD];   // 25600 B
  __shared__ float red_m1[4][64];
  __shared__ float red_m2[4][64];

  const int t    = threadIdx.x;
  const int lane = t & 63;
  const int w    = t >> 6;        // wave id = 32-col slice of each 128-col chunk
  const int l15  = lane & 15;
  const int g4   = lane >> 4;

  const int n0  = blockIdx.x * 64;
  const int b   = n0 >> 10;
  const int hw0 = n0 & (HW - 1);

  // ---- stage A: load x (coalesced across rows), trunc-split, pack [hi|lo|hi] ----
  {
    const int r = t & 63, q = t >> 6;             // row, 16-channel quarter
    const float* xb = xin + (size_t)b * (CDIM * HW) + hw0 + r;
    unsigned short* arow = A_s + r * APAD;
#pragma unroll
    for (int u = 0; u < 8; ++u) {
      const int c0 = q * 16 + 2 * u;
      const float v0 = xb[(size_t)c0 * HW];
      const float v1 = xb[(size_t)(c0 + 1) * HW];
      const unsigned int h0 = __float_as_uint(v0) >> 16;
      const unsigned int h1 = __float_as_uint(v1) >> 16;
      const float r0 = v0 - __uint_as_float(h0 << 16);
      const float r1 = v1 - __uint_as_float(h1 << 16);
      const unsigned int lo0 = __float_as_uint(r0) >> 16;
      const unsigned int lo1 = __float_as_uint(r1) >> 16;
      const unsigned int hh = h0 | (h1 << 16);
      const unsigned int ll = lo0 | (lo1 << 16);
      *(unsigned int*)(arow + c0)        = hh;   // slots [0,64):   x_hi
      *(unsigned int*)(arow + 64 + c0)   = ll;   // slots [64,128): x_lo
      *(unsigned int*)(arow + 128 + c0)  = hh;   // slots [128,192):x_hi
    }
  }
  __syncthreads();

  float m1[16], m2[16];
#pragma unroll
  for (int i = 0; i < 16; ++i) { m1[i] = INFINITY; m2[i] = INFINITY; }

  // per-lane A fragment base (bf16 elems); rt adds 16*APAD, s adds 32
  const unsigned short* aF = A_s + l15 * APAD + g4 * 8;
  // per-lane B pointers for (ct0, ct1); s adds 32, chunk adds 128*BPAD
  const unsigned short* pB = esp + (size_t)(w * 32 + l15) * BPAD + g4 * 8;
  const float* pN = norms + w * 32 + l15;

  // preloaded s=0 fragments of the current chunk (carried across iterations;
  // last iteration's extra preload reads harmless in-bounds garbage past esp)
  bf16x8 c0 = *(const bf16x8*)(pB);
  bf16x8 c1 = *(const bf16x8*)(pB + 16 * BPAD);

#pragma unroll 1
  for (int cb = 0; cb < 8; ++cb) {
    const float nk0 = pN[0];
    const float nk1 = pN[16];

    f32x4 acc[4][2];
#pragma unroll
    for (int rt = 0; rt < 4; ++rt)
#pragma unroll
      for (int ct = 0; ct < 2; ++ct)
        acc[rt][ct] = (f32x4){0.0f, 0.0f, 0.0f, 0.0f};

    // s = 0 uses the preloaded pair
    {
      const bf16x8 a0 = *(const bf16x8*)(aF);
      const bf16x8 a1 = *(const bf16x8*)(aF + 16 * APAD);
      const bf16x8 a2 = *(const bf16x8*)(aF + 32 * APAD);
      const bf16x8 a3 = *(const bf16x8*)(aF + 48 * APAD);
      acc[0][0] = __builtin_amdgcn_mfma_f32_16x16x32_bf16(a0, c0, acc[0][0], 0, 0, 0);
      acc[1][0] = __builtin_amdgcn_mfma_f32_16x16x32_bf16(a1, c0, acc[1][0], 0, 0, 0);
      acc[2][0] = __builtin_amdgcn_mfma_f32_16x16x32_bf16(a2, c0, acc[2][0], 0, 0, 0);
      acc[3][0] = __builtin_amdgcn_mfma_f32_16x16x32_bf16(a3, c0, acc[3][0], 0, 0, 0);
      acc[0][1] = __builtin_amdgcn_mfma_f32_16x16x32_bf16(a0, c1, acc[0][1], 0, 0, 0);
      acc[1][1] = __builtin_amdgcn_mfma_f32_16x16x32_bf16(a1, c1, acc[1][1], 0, 0, 0);
      acc[2][1] = __builtin_amdgcn_mfma_f32_16x16x32_bf16(a2, c1, acc[2][1], 0, 0, 0);
      acc[3][1] = __builtin_amdgcn_mfma_f32_16x16x32_bf16(a3, c1, acc[3][1], 0, 0, 0);
    }
#pragma unroll
    for (int s = 1; s < 6; ++s) {
      const bf16x8 b0 = *(const bf16x8*)(pB + s * 32);
      const bf16x8 b1 = *(const bf16x8*)(pB + 16 * BPAD + s * 32);
      const bf16x8 a0 = *(const bf16x8*)(aF + s * 32);
      const bf16x8 a1 = *(const bf16x8*)(aF + 16 * APAD + s * 32);
      const bf16x8 a2 = *(const bf16x8*)(aF + 32 * APAD + s * 32);
      const bf16x8 a3 = *(const bf16x8*)(aF + 48 * APAD + s * 32);
      acc[0][0] = __builtin_amdgcn_mfma_f32_16x16x32_bf16(a0, b0, acc[0][0], 0, 0, 0);
      acc[1][0] = __builtin_amdgcn_mfma_f32_16x16x32_bf16(a1, b0, acc[1][0], 0, 0, 0);
      acc[2][0] = __builtin_amdgcn_mfma_f32_16x16x32_bf16(a2, b0, acc[2][0], 0, 0, 0);
      acc[3][0] = __builtin_amdgcn_mfma_f32_16x16x32_bf16(a3, b0, acc[3][0], 0, 0, 0);
      acc[0][1] = __builtin_amdgcn_mfma_f32_16x16x32_bf16(a0, b1, acc[0][1], 0, 0, 0);
      acc[1][1] = __builtin_amdgcn_mfma_f32_16x16x32_bf16(a1, b1, acc[1][1], 0, 0, 0);
      acc[2][1] = __builtin_amdgcn_mfma_f32_16x16x32_bf16(a2, b1, acc[2][1], 0, 0, 0);
      acc[3][1] = __builtin_amdgcn_mfma_f32_16x16x32_bf16(a3, b1, acc[3][1], 0, 0, 0);
    }

    const unsigned kbase = (unsigned)(cb * 128 + w * 32 + l15);
    pB += 128 * BPAD;
    pN += 128;
    // preload next chunk's s=0 pair; hides L2 latency under the epilogue VALU
    c0 = *(const bf16x8*)(pB);
    c1 = *(const bf16x8*)(pB + 16 * BPAD);

    // epilogue: g~ = nk - 2*dot~, pack col idx into low 10 mantissa bits, fminf-track.
#pragma unroll
    for (int ct = 0; ct < 2; ++ct) {
      const float nk = ct ? nk1 : nk0;
      const unsigned kcol = kbase + (unsigned)(ct * 16);
#pragma unroll
      for (int rt = 0; rt < 4; ++rt) {
#pragma unroll
        for (int rg = 0; rg < 4; ++rg) {
          const float g  = fmaf(-2.0f, acc[rt][ct][rg], nk);
          const float gp = __uint_as_float((__float_as_uint(g) & 0xFFFFFC00u) | kcol);
          const int   si = rt * 4 + rg;
          m2[si] = fminf(m2[si], fmaxf(m1[si], gp));
          m1[si] = fminf(m1[si], gp);
        }
      }
    }
  }

  // butterfly merge across the 16 col-lanes (packed: no index shuffles needed)
#pragma unroll
  for (int mask = 1; mask <= 8; mask <<= 1) {
#pragma unroll
    for (int si = 0; si < 16; ++si) {
      const float om1 = __shfl_xor(m1[si], mask, 64);
      const float om2 = __shfl_xor(m2[si], mask, 64);
      m2[si] = fminf(fminf(m2[si], om2), fmaxf(m1[si], om1));
      m1[si] = fminf(m1[si], om1);
    }
  }
  if (l15 == 0) {
#pragma unroll
    for (int rt = 0; rt < 4; ++rt)
#pragma unroll
      for (int rg = 0; rg < 4; ++rg) {
        const int row = rt * 16 + g4 * 4 + rg;
        red_m1[w][row] = m1[rt * 4 + rg];
        red_m2[w][row] = m2[rt * 4 + rg];
      }
  }
  __syncthreads();
  if (t < 64) {
    float M1 = red_m1[0][t], M2 = red_m2[0][t];
#pragma unroll
    for (int ww = 1; ww < 4; ++ww) {
      const float om1 = red_m1[ww][t], om2 = red_m2[ww][t];
      M2 = fminf(fminf(M2, om2), fmaxf(M1, om1));
      M1 = fminf(M1, om1);
    }
    const int K1 = (int)(__float_as_uint(M1) & 1023u);
    out_idx[n0 + t] = (float)K1;     // best guess; flagged rows fixed by rescan
    if (M2 - M1 <= EPS_THR) {        // gap too small -> exact rescan required
      const unsigned pos = atomicAdd(nflag, 1u);
      flaglist[pos] = (unsigned)(n0 + t);
    }
  }
}

// Pass 2b: exact rescan, block-cooperative LDS staging (r4 rewrite).
// 16 flagged rows per block share LDS-staged 128-code chunks (coalesced float4
// staging; EPADR=68 pad -> 2-way read conflict = free). Thread (rr,tk) owns row rr
// and codes k = cb*128 + j*16 + tk (ascending) with the bit-exact serial FMA chain;
// lexicographic (d,k) butterfly over the 16-lane row group = np first-min.
__global__ __launch_bounds__(256)
void vq_rescan(const float* __restrict__ xin, const float* __restrict__ emb,
               const float* __restrict__ norms,
               const unsigned int* __restrict__ nflag,
               const unsigned int* __restrict__ flaglist,
               float* __restrict__ out_idx)
{
  __shared__ __align__(16) float e_s[128 * EPADR];   // 34816 B
  __shared__ float x_s[RSROWS * EPADR];              // 4352 B
  const int t  = threadIdx.x;
  const int rr = t >> 4;    // row slot 0..15
  const int tk = t & 15;    // k-lane within row group
  const unsigned nf = *nflag;

  for (unsigned base = blockIdx.x * RSROWS; base < nf; base += gridDim.x * RSROWS) {
    const unsigned ridx  = base + (unsigned)rr;
    const bool     active = ridx < nf;
    const int n  = (int)flaglist[active ? ridx : (nf - 1)];   // clamp: safe dummy row
    const int bb = n >> 10, hw = n & (HW - 1);

    // stage this row's x: 16 threads/row x 4 channels each
    {
      const float* xb = xin + (size_t)bb * (CDIM * HW) + hw;
#pragma unroll
      for (int j = 0; j < 4; ++j) {
        const int c = tk * 4 + j;
        x_s[rr * EPADR + c] = xb[(size_t)c * HW];
      }
    }
    __syncthreads();

    // per-thread register copy of its row (static indexing; ~64 VGPR)
    float xr[CDIM];
#pragma unroll
    for (int c = 0; c < CDIM; ++c) xr[c] = x_s[rr * EPADR + c];
    const float S = np_sumsq64(xr);

    float dmin = INFINITY; int kmin = 0;

    for (int cb = 0; cb < 8; ++cb) {
      __syncthreads();   // previous chunk's readers done before overwrite
      // stage 128 codes: 8192 floats = 2048 float4, 8 per thread, coalesced
      {
        const float4* src = (const float4*)(emb + (size_t)cb * 128 * CDIM);
#pragma unroll
        for (int i = 0; i < 8; ++i) {
          const int f    = i * 256 + t;
          const int code = f >> 4, c4 = f & 15;
          *(float4*)(e_s + code * EPADR + c4 * 4) = src[f];
        }
      }
      __syncthreads();

#pragma unroll 2
      for (int j = 0; j < 8; ++j) {
        const int kk = j * 16 + tk;
        const float* er = e_s + kk * EPADR;
        float d = 0.0f;
#pragma unroll
        for (int c4 = 0; c4 < 16; ++c4) {    // exact reference chain, c ascending
          const float4 a = *(const float4*)(er + 4 * c4);
          d = fmaf(xr[4*c4+0], a.x, d);
          d = fmaf(xr[4*c4+1], a.y, d);
          d = fmaf(xr[4*c4+2], a.z, d);
          d = fmaf(xr[4*c4+3], a.w, d);
        }
        const int k = cb * 128 + kk;
        const float q = (S - 2.0f * d) + norms[k];
        if (q < dmin) { dmin = q; kmin = k; }   // strict < keeps first (lowest k)
      }
    }

    // lexicographic (d,k) first-min across the 16-lane row group
#pragma unroll
    for (int mask = 1; mask <= 8; mask <<= 1) {
      const float od = __shfl_xor(dmin, mask, 64);
      const int   ok = __shfl_xor(kmin, mask, 64);
      if (od < dmin || (od == dmin && ok < kmin)) { dmin = od; kmin = ok; }
    }
    if (active && tk == 0) out_idx[n] = (float)kmin;
    __syncthreads();   // all done with x_s/e_s before next group restages
  }
}

// Pass 2a: epilogue for ALL rows — identical arithmetic & partials structure to the
// previously-passing kernel (1024 blocks x 64 rows, same shfl reduce order).
__global__ __launch_bounds__(64)
void vq_epilogue(const float* __restrict__ xin, const float* __restrict__ emb,
                 const float* __restrict__ out_idx, float* __restrict__ out0,
                 double* __restrict__ partials, unsigned int* __restrict__ counts)
{
  __shared__ unsigned int hist_s[NUM_K];
  const int t = threadIdx.x;
  const int n = blockIdx.x * 64 + t;
  for (int i = t; i < NUM_K; i += 64) hist_s[i] = 0;
  __syncthreads();
  const int bb = n >> 10, hw = n & (HW - 1);
  const float* xb = xin + (size_t)bb * (CDIM * HW) + hw;
  int kmin = (int)out_idx[n];
  if (kmin < 0) kmin = 0;                     // safety clamp (should not happen)
  atomicAdd(&hist_s[kmin], 1u);
  const float4* eb = (const float4*)(emb + (size_t)kmin * CDIM);
  float4* o = (float4*)(out0 + (size_t)n * CDIM);
  float ssq = 0.0f;
#pragma unroll
  for (int c4 = 0; c4 < 16; ++c4) {
    const float4 q4 = eb[c4];
    const float x0 = xb[(4*c4+0) * HW], x1 = xb[(4*c4+1) * HW];
    const float x2 = xb[(4*c4+2) * HW], x3 = xb[(4*c4+3) * HW];
    const float u0 = q4.x - x0, u1 = q4.y - x1, u2 = q4.z - x2, u3 = q4.w - x3;
    ssq = fmaf(u0, u0, fmaf(u1, u1, fmaf(u2, u2, fmaf(u3, u3, ssq))));
    o[c4] = make_float4(x0 + u0, x1 + u1, x2 + u2, x3 + u3);
  }
#pragma unroll
  for (int off = 32; off > 0; off >>= 1) ssq += __shfl_down(ssq, off, 64);
  if (t == 0) partials[blockIdx.x] = (double)ssq;   // deterministic, no FP atomics
  __syncthreads();
  for (int i = t; i < NUM_K; i += 64) {
    const unsigned int v = hist_s[i];
    if (v) atomicAdd(&counts[i], v);
  }
}

__global__ void vq_final(const double* __restrict__ partials,
                         const unsigned int* __restrict__ counts,
                         float* __restrict__ out_loss, float* __restrict__ out_perp)
{
  __shared__ double sh[256];
  const int t = threadIdx.x;
  double acc = 0.0, ent = 0.0;
  for (int i = t; i < NBLK; i += 256) acc += partials[i];
  for (int k = t; k < NUM_K; k += 256) {
    const double pr = (double)counts[k] * (1.0 / 65536.0);
    ent += pr * log(pr + 1e-10);
  }
  sh[t] = acc;
  __syncthreads();
  for (int s = 128; s > 0; s >>= 1) { if (t < s) sh[t] += sh[t + s]; __syncthreads(); }
  const double total = sh[0];
  __syncthreads();
  sh[t] = ent;
  __syncthreads();
  for (int s = 128; s > 0; s >>= 1) { if (t < s) sh[t] += sh[t + s]; __syncthreads(); }
  if (t == 0) {
    out_loss[0] = (float)(1.25 * total / 4194304.0);
    out_perp[0] = (float)exp(-sh[0]);
  }
}

extern "C" void kernel_launch(void* const* d_in, const int* in_sizes, int n_in,
                              void* d_out, int out_size, void* d_ws, size_t ws_size,
                              hipStream_t stream)
{
  const float* xin = (const float*)d_in[0];
  const float* emb = (const float*)d_in[1];
  float* out = (float*)d_out;

  // ws layout: [0,4K) fp32 norms[1024] | [4K,8K) u32 counts[1024] | [8K,16K) f64 partials[1024]
  float*        norms    = (float*)d_ws;
  unsigned int* counts   = (unsigned int*)((char*)d_ws + 4096);
  double*       partials = (double*)((char*)d_ws + 8192);

  float* out0     = out;                       // 4194304 elements (BHWC flat)
  float* out_loss = out + 4194304;             // scalar
  float* out_idx  = out + 4194305;             // 65536 elements (as float)
  float* out_perp = out + 4194305 + 65536;     // scalar

  // scratch stashed in out0 (consumed before vq_epilogue overwrites it):
  //   [0, 448K)           split codebook e' (1024 x 224 bf16)
  //   [8M, 8M+4)          u32 flag counter
  //   [8M+4, 8M+4+256K)   u32 flaglist (worst case 65536 rows)
  unsigned short* esp      = (unsigned short*)out0;
  unsigned int*   nflag    = (unsigned int*)((char*)out0 + (8u << 20));
  unsigned int*   flaglist = nflag + 1;

  hipMemsetAsync((char*)d_ws + 4096, 0, 4096, stream);  // zero counts
  hipMemsetAsync(nflag, 0, 4, stream);                  // zero flag counter

  vq_prep    <<<dim3(16),   dim3(64),  0, stream>>>(emb, norms, esp);
  vq_dist    <<<dim3(1024), dim3(256), 0, stream>>>(xin, norms, esp, out_idx,
                                                    nflag, flaglist);
  vq_rescan  <<<dim3(512),  dim3(256), 0, stream>>>(xin, emb, norms, nflag,
                                                    flaglist, out_idx);
  vq_epilogue<<<dim3(1024), dim3(64),  0, stream>>>(xin, emb, out_idx, out0, partials, counts);
  vq_final   <<<dim3(1),    dim3(256), 0, stream>>>(partials, counts, out_loss, out_perp);
}